// Round 2
// baseline (870.987 us; speedup 1.0000x reference)
//
#include <hip/hip_runtime.h>
#include <math.h>

#define N_NODES 100000
#define N_EDGES 1600000
#define OUTC 40

#define RANGE 16384                 // nodes per LDS histogram (64 KB)
#define NR 7                        // 7*16384 = 114688 >= N
#define NPAD (NR * RANGE)           // 114688
#define NC 16                       // edge chunks
#define CHUNK (N_EDGES / NC)        // 100000 exact

#define SCAN_BLOCK 1024
#define SCAN_NBLK ((N_NODES + SCAN_BLOCK - 1) / SCAN_BLOCK)   // 98

// ---------------- histogram: per-(chunk, range) counts, LDS atomics only ----------------
__global__ __launch_bounds__(256) void k_hist(const int* __restrict__ src,
                                              const int* __restrict__ dst,
                                              int* __restrict__ Hs,
                                              int* __restrict__ Hd) {
    __shared__ int hist[RANGE];
    int c = blockIdx.x, r = blockIdx.y;
    const int* a = blockIdx.z ? dst : src;
    int* H = blockIdx.z ? Hd : Hs;
    for (int k = threadIdx.x; k < RANGE; k += 256) hist[k] = 0;
    __syncthreads();
    int r0 = r * RANGE;
    int e0 = c * CHUNK, e1 = e0 + CHUNK;
    for (int e = e0 + threadIdx.x; e < e1; e += 256) {
        unsigned d = (unsigned)(a[e] - r0);
        if (d < RANGE) atomicAdd(&hist[d], 1);
    }
    __syncthreads();
    for (int k = threadIdx.x; k < RANGE; k += 256) H[c * NPAD + r0 + k] = hist[k];
}

// deg_src = column-sum of Hs; maxdeg via wave-max + few atomics
__global__ __launch_bounds__(256) void k_degsrc(const int* __restrict__ Hs,
                                                int* __restrict__ deg_src,
                                                int* __restrict__ maxdeg) {
    int i = blockIdx.x * 256 + threadIdx.x;
    int v = 0;
    if (i < N_NODES) {
        #pragma unroll
        for (int c = 0; c < NC; c++) v += Hs[c * NPAD + i];
        deg_src[i] = v;
    }
    int m = v;
    for (int off = 32; off; off >>= 1) m = max(m, __shfl_down(m, off));
    if ((threadIdx.x & 63) == 0) atomicMax(maxdeg, m);
}

// inclusive scan of deg_dst (= column-sum of Hd) per 1024-chunk -> rowptr[i+1]
__global__ __launch_bounds__(SCAN_BLOCK) void k_scan1(const int* __restrict__ Hd,
                                                      int* __restrict__ rowptr,
                                                      int* __restrict__ blocksum) {
    __shared__ int buf[2][SCAN_BLOCK];
    int t = threadIdx.x;
    int i = blockIdx.x * SCAN_BLOCK + t;
    int v = 0;
    if (i < N_NODES) {
        #pragma unroll
        for (int c = 0; c < NC; c++) v += Hd[c * NPAD + i];
    }
    int cur = 0;
    buf[0][t] = v;
    __syncthreads();
    for (int off = 1; off < SCAN_BLOCK; off <<= 1) {
        int nv = buf[cur][t];
        if (t >= off) nv += buf[cur][t - off];
        buf[1 - cur][t] = nv;
        cur = 1 - cur;
        __syncthreads();
    }
    int incl = buf[cur][t];
    if (i < N_NODES) rowptr[i + 1] = incl;
    if (t == SCAN_BLOCK - 1) blocksum[blockIdx.x] = incl;
}

__global__ __launch_bounds__(SCAN_BLOCK) void k_scan2(int* __restrict__ rowptr,
                                                      const int* __restrict__ blocksum) {
    __shared__ int offs[SCAN_NBLK];
    if (threadIdx.x == 0) {
        int run = 0;
        for (int b = 0; b < SCAN_NBLK; b++) { offs[b] = run; run += blocksum[b]; }
        rowptr[0] = 0;
    }
    __syncthreads();
    for (int i = threadIdx.x; i < N_NODES; i += SCAN_BLOCK)
        rowptr[i + 1] += offs[i / SCAN_BLOCK];
}

// Hd[c][d] := rowptr[d] + sum_{c'<c} Hd[c'][d]   (in-place -> base positions)
__global__ __launch_bounds__(256) void k_basepos(const int* __restrict__ rowptr,
                                                 int* __restrict__ Hd) {
    int i = blockIdx.x * 256 + threadIdx.x;
    if (i >= N_NODES) return;
    int run = rowptr[i];
    #pragma unroll
    for (int c = 0; c < NC; c++) {
        int t = Hd[c * NPAD + i];
        Hd[c * NPAD + i] = run;
        run += t;
    }
}

// counting-sort fill: LDS position counters, no global atomics
__global__ __launch_bounds__(256) void k_fill2(const int* __restrict__ src,
                                               const int* __restrict__ dst,
                                               const int* __restrict__ basepos,
                                               int* __restrict__ csr_src) {
    __shared__ int pos[RANGE];
    int c = blockIdx.x, r = blockIdx.y;
    int r0 = r * RANGE;
    for (int k = threadIdx.x; k < RANGE; k += 256) pos[k] = basepos[c * NPAD + r0 + k];
    __syncthreads();
    int e0 = c * CHUNK, e1 = e0 + CHUNK;
    for (int e = e0 + threadIdx.x; e < e1; e += 256) {
        int s = src[e];
        unsigned d = (unsigned)(dst[e] - r0);
        if (d < RANGE) {
            int p = atomicAdd(&pos[d], 1);
            csr_src[p] = s;
        }
    }
}

// ---------------- GEMM: G0 = h@W0 + b, G1 = h@W1 (64 -> 64) ----------------
__global__ __launch_bounds__(256) void k_gemm64(const float* __restrict__ h,
                                                const float* __restrict__ W0,
                                                const float* __restrict__ W1,
                                                const float* __restrict__ b,
                                                float* __restrict__ G0,
                                                float* __restrict__ G1) {
    __shared__ float sw0[64 * 64], sw1[64 * 64];
    __shared__ float sh[4 * 64];
    int t = threadIdx.x;
    for (int k = t; k < 64 * 64; k += 256) { sw0[k] = W0[k]; sw1[k] = W1[k]; }
    int r = t >> 6, c = t & 63;
    int i = blockIdx.x * 4 + r;    // grid exactly N/4
    sh[t] = h[i * 64 + c];
    __syncthreads();
    float a0 = b[c], a1 = 0.f;
    #pragma unroll
    for (int k = 0; k < 64; k++) {
        float hv = sh[r * 64 + k];
        a0 += hv * sw0[k * 64 + c];
        a1 += hv * sw1[k * 64 + c];
    }
    G0[i * 64 + c] = a0;
    G1[i * 64 + c] = a1;
}

// ---------------- GEMM: 64 -> 40 ----------------
__global__ __launch_bounds__(256) void k_gemm40(const float* __restrict__ h,
                                                const float* __restrict__ W0,
                                                const float* __restrict__ W1,
                                                const float* __restrict__ b,
                                                float* __restrict__ G0,
                                                float* __restrict__ G1) {
    __shared__ float sw0[64 * OUTC], sw1[64 * OUTC];
    __shared__ float sh[4 * 64];
    int t = threadIdx.x;
    for (int k = t; k < 64 * OUTC; k += 256) { sw0[k] = W0[k]; sw1[k] = W1[k]; }
    int r = t >> 6, c = t & 63;
    int i = blockIdx.x * 4 + r;
    sh[t] = h[i * 64 + c];
    __syncthreads();
    if (c >= OUTC) return;
    float a0 = b[c], a1 = 0.f;
    #pragma unroll
    for (int k = 0; k < 64; k++) {
        float hv = sh[r * 64 + k];
        a0 += hv * sw0[k * OUTC + c];
        a1 += hv * sw1[k * OUTC + c];
    }
    G0[i * OUTC + c] = a0;
    G1[i * OUTC + c] = a1;
}

// ---------------- fused SpMM + epilogue (relu), 64 ch ----------------
// out[i] = relu( G0[i] + norm_loop[i]*G1[i] - scale * sum_{e: dst=i} G1[src_e] )
__global__ __launch_bounds__(256) void k_spmm64(const float* __restrict__ G0,
                                                const float* __restrict__ G1,
                                                const int* __restrict__ rowptr,
                                                const int* __restrict__ csr_src,
                                                const int* __restrict__ deg_src,
                                                const int* __restrict__ maxdeg,
                                                float* __restrict__ out) {
    int wave = threadIdx.x >> 6;
    int lane = threadIdx.x & 63;
    int i = blockIdx.x * 4 + wave;
    float scale = 1.0f / (float)(*maxdeg);
    float g0 = G0[i * 64 + lane];
    float g1 = G1[i * 64 + lane];
    int e0 = rowptr[i], e1 = rowptr[i + 1];
    float acc0 = 0.f, acc1 = 0.f;
    for (int base = e0; base < e1; base += 64) {
        int n = min(64, e1 - base);
        int idx = (base + lane < e1) ? csr_src[base + lane] : 0;
        int j = 0;
        for (; j + 4 <= n; j += 4) {
            int s0 = __shfl(idx, j);
            int s1 = __shfl(idx, j + 1);
            int s2 = __shfl(idx, j + 2);
            int s3 = __shfl(idx, j + 3);
            float a0 = G1[s0 * 64 + lane];
            float a1 = G1[s1 * 64 + lane];
            float a2 = G1[s2 * 64 + lane];
            float a3 = G1[s3 * 64 + lane];
            acc0 += a0 + a2;
            acc1 += a1 + a3;
        }
        for (; j < n; j++) {
            int s = __shfl(idx, j);
            acc0 += G1[s * 64 + lane];
        }
    }
    float nl = (float)deg_src[i] * scale - 1.0f;
    float v = g0 + nl * g1 - scale * (acc0 + acc1);
    out[i * 64 + lane] = fmaxf(v, 0.f);
}

// ---------------- fused SpMM + log_softmax, 40 ch ----------------
__global__ __launch_bounds__(256) void k_spmm40(const float* __restrict__ G0,
                                                const float* __restrict__ G1,
                                                const int* __restrict__ rowptr,
                                                const int* __restrict__ csr_src,
                                                const int* __restrict__ deg_src,
                                                const int* __restrict__ maxdeg,
                                                float* __restrict__ out) {
    int wave = threadIdx.x >> 6;
    int lane = threadIdx.x & 63;
    int i = blockIdx.x * 4 + wave;
    float scale = 1.0f / (float)(*maxdeg);
    bool act = lane < OUTC;
    float g0 = act ? G0[i * OUTC + lane] : 0.f;
    float g1 = act ? G1[i * OUTC + lane] : 0.f;
    int e0 = rowptr[i], e1 = rowptr[i + 1];
    float acc0 = 0.f, acc1 = 0.f;
    for (int base = e0; base < e1; base += 64) {
        int n = min(64, e1 - base);
        int idx = (base + lane < e1) ? csr_src[base + lane] : 0;
        int j = 0;
        for (; j + 4 <= n; j += 4) {
            int s0 = __shfl(idx, j);
            int s1 = __shfl(idx, j + 1);
            int s2 = __shfl(idx, j + 2);
            int s3 = __shfl(idx, j + 3);
            if (act) {
                float a0 = G1[s0 * OUTC + lane];
                float a1 = G1[s1 * OUTC + lane];
                float a2 = G1[s2 * OUTC + lane];
                float a3 = G1[s3 * OUTC + lane];
                acc0 += a0 + a2;
                acc1 += a1 + a3;
            }
        }
        for (; j < n; j++) {
            int s = __shfl(idx, j);
            if (act) acc0 += G1[s * OUTC + lane];
        }
    }
    float nl = (float)deg_src[i] * scale - 1.0f;
    float v = g0 + nl * g1 - scale * (acc0 + acc1);
    float x = act ? v : -INFINITY;
    float m = x;
    for (int off = 32; off; off >>= 1) m = fmaxf(m, __shfl_xor(m, off));
    float ex = act ? __expf(v - m) : 0.f;
    float s = ex;
    for (int off = 32; off; off >>= 1) s += __shfl_xor(s, off);
    if (act) out[i * OUTC + lane] = v - m - __logf(s);
}

// ---------------- launch ----------------

extern "C" void kernel_launch(void* const* d_in, const int* in_sizes, int n_in,
                              void* d_out, int out_size, void* d_ws, size_t ws_size,
                              hipStream_t stream) {
    const float* x   = (const float*)d_in[0];
    const int* ei    = (const int*)d_in[1];
    const int* src   = ei;
    const int* dst   = ei + N_EDGES;
    const float* W0_0 = (const float*)d_in[2];
    const float* W1_0 = (const float*)d_in[3];
    const float* b_0  = (const float*)d_in[4];
    const float* W0_1 = (const float*)d_in[5];
    const float* W1_1 = (const float*)d_in[6];
    const float* b_1  = (const float*)d_in[7];
    const float* W0_2 = (const float*)d_in[8];
    const float* W1_2 = (const float*)d_in[9];
    const float* b_2  = (const float*)d_in[10];
    float* outp = (float*)d_out;

    // workspace layout
    int* ip = (int*)d_ws;
    int* deg_src  = ip;                      // N
    int* rowptr   = ip + 100000;             // N+1 (padded to 100032)
    int* blocksum = ip + 200064;             // 128
    int* maxdeg   = ip + 200192;             // 1 (padded to 64)
    int* csr_src  = ip + 200256;             // E
    float* fb = (float*)(ip + 1800256);
    float* hbuf = fb;                        // N*64
    float* G0   = fb + 6400000;              // N*64
    float* G1   = fb + 12800000;             // N*64
    // during CSR build, reuse G0/G1 space for histograms (NC*NPAD = 1.83M ints each)
    int* Hs = (int*)G0;
    int* Hd = (int*)G1;

    hipMemsetAsync(maxdeg, 0, sizeof(int), stream);

    k_hist<<<dim3(NC, NR, 2), 256, 0, stream>>>(src, dst, Hs, Hd);
    k_degsrc<<<(N_NODES + 255) / 256, 256, 0, stream>>>(Hs, deg_src, maxdeg);
    k_scan1<<<SCAN_NBLK, SCAN_BLOCK, 0, stream>>>(Hd, rowptr, blocksum);
    k_scan2<<<1, SCAN_BLOCK, 0, stream>>>(rowptr, blocksum);
    k_basepos<<<(N_NODES + 255) / 256, 256, 0, stream>>>(rowptr, Hd);
    k_fill2<<<dim3(NC, NR), 256, 0, stream>>>(src, dst, Hd, csr_src);

    const int GN = N_NODES / 4;   // 25000, exact

    // layer 0: x -> hbuf
    k_gemm64<<<GN, 256, 0, stream>>>(x, W0_0, W1_0, b_0, G0, G1);
    k_spmm64<<<GN, 256, 0, stream>>>(G0, G1, rowptr, csr_src, deg_src, maxdeg, hbuf);
    // layer 1: hbuf -> hbuf (in-place safe: spmm reads only G0/G1)
    k_gemm64<<<GN, 256, 0, stream>>>(hbuf, W0_1, W1_1, b_1, G0, G1);
    k_spmm64<<<GN, 256, 0, stream>>>(G0, G1, rowptr, csr_src, deg_src, maxdeg, hbuf);
    // layer 2: hbuf -> out (40 ch + log_softmax)
    k_gemm40<<<GN, 256, 0, stream>>>(hbuf, W0_2, W1_2, b_2, G0, G1);
    k_spmm40<<<GN, 256, 0, stream>>>(G0, G1, rowptr, csr_src, deg_src, maxdeg, outp);
}

// Round 3
// 503.982 us; speedup vs baseline: 1.7282x; 1.7282x over previous
//
#include <hip/hip_runtime.h>
#include <math.h>

#define N_NODES 100000
#define N_EDGES 1600000
#define OUTC 40

#define RANGE 16384                 // nodes per LDS histogram (64 KB)
#define NR 7                        // 7*16384 = 114688 >= N
#define NPAD (NR * RANGE)           // 114688
#define NC 32                       // edge chunks
#define CHUNK (N_EDGES / NC)        // 50000 exact

#define SCAN_BLOCK 1024
#define SCAN_NBLK ((N_NODES + SCAN_BLOCK - 1) / SCAN_BLOCK)   // 98

// ---------------- histogram: per-(chunk, range) counts, LDS atomics only ----------------
__global__ __launch_bounds__(1024) void k_hist(const int* __restrict__ src,
                                               const int* __restrict__ dst,
                                               int* __restrict__ Hs,
                                               int* __restrict__ Hd) {
    __shared__ int hist[RANGE];
    int c = blockIdx.x, r = blockIdx.y;
    const int* a = blockIdx.z ? dst : src;
    int* H = blockIdx.z ? Hd : Hs;
    for (int k = threadIdx.x; k < RANGE; k += 1024) hist[k] = 0;
    __syncthreads();
    int r0 = r * RANGE;
    int e0 = c * CHUNK, e1 = e0 + CHUNK;
    for (int e = e0 + threadIdx.x; e < e1; e += 1024) {
        unsigned d = (unsigned)(a[e] - r0);
        if (d < RANGE) atomicAdd(&hist[d], 1);
    }
    __syncthreads();
    for (int k = threadIdx.x; k < RANGE; k += 1024) H[c * NPAD + r0 + k] = hist[k];
}

// deg_src = column-sum of Hs; maxdeg via wave-max + few atomics
__global__ __launch_bounds__(256) void k_degsrc(const int* __restrict__ Hs,
                                                int* __restrict__ deg_src,
                                                int* __restrict__ maxdeg) {
    int i = blockIdx.x * 256 + threadIdx.x;
    int v = 0;
    if (i < N_NODES) {
        #pragma unroll
        for (int c = 0; c < NC; c++) v += Hs[c * NPAD + i];
        deg_src[i] = v;
    }
    int m = v;
    for (int off = 32; off; off >>= 1) m = max(m, __shfl_down(m, off));
    if ((threadIdx.x & 63) == 0) atomicMax(maxdeg, m);
}

// inclusive scan of deg_dst (= column-sum of Hd) per 1024-chunk -> rowptr[i+1]
__global__ __launch_bounds__(SCAN_BLOCK) void k_scan1(const int* __restrict__ Hd,
                                                      int* __restrict__ rowptr,
                                                      int* __restrict__ blocksum) {
    __shared__ int buf[2][SCAN_BLOCK];
    int t = threadIdx.x;
    int i = blockIdx.x * SCAN_BLOCK + t;
    int v = 0;
    if (i < N_NODES) {
        #pragma unroll
        for (int c = 0; c < NC; c++) v += Hd[c * NPAD + i];
    }
    int cur = 0;
    buf[0][t] = v;
    __syncthreads();
    for (int off = 1; off < SCAN_BLOCK; off <<= 1) {
        int nv = buf[cur][t];
        if (t >= off) nv += buf[cur][t - off];
        buf[1 - cur][t] = nv;
        cur = 1 - cur;
        __syncthreads();
    }
    int incl = buf[cur][t];
    if (i < N_NODES) rowptr[i + 1] = incl;
    if (t == SCAN_BLOCK - 1) blocksum[blockIdx.x] = incl;
}

__global__ __launch_bounds__(SCAN_BLOCK) void k_scan2(int* __restrict__ rowptr,
                                                      const int* __restrict__ blocksum) {
    __shared__ int offs[SCAN_NBLK];
    if (threadIdx.x == 0) {
        int run = 0;
        for (int b = 0; b < SCAN_NBLK; b++) { offs[b] = run; run += blocksum[b]; }
        rowptr[0] = 0;
    }
    __syncthreads();
    for (int i = threadIdx.x; i < N_NODES; i += SCAN_BLOCK)
        rowptr[i + 1] += offs[i / SCAN_BLOCK];
}

// Hd[c][d] := rowptr[d] + sum_{c'<c} Hd[c'][d]   (in-place -> base positions)
__global__ __launch_bounds__(256) void k_basepos(const int* __restrict__ rowptr,
                                                 int* __restrict__ Hd) {
    int i = blockIdx.x * 256 + threadIdx.x;
    if (i >= N_NODES) return;
    int run = rowptr[i];
    #pragma unroll
    for (int c = 0; c < NC; c++) {
        int t = Hd[c * NPAD + i];
        Hd[c * NPAD + i] = run;
        run += t;
    }
}

// counting-sort fill: LDS position counters, no global atomics
__global__ __launch_bounds__(1024) void k_fill2(const int* __restrict__ src,
                                                const int* __restrict__ dst,
                                                const int* __restrict__ basepos,
                                                int* __restrict__ csr_src) {
    __shared__ int pos[RANGE];
    int c = blockIdx.x, r = blockIdx.y;
    int r0 = r * RANGE;
    for (int k = threadIdx.x; k < RANGE; k += 1024) pos[k] = basepos[c * NPAD + r0 + k];
    __syncthreads();
    int e0 = c * CHUNK, e1 = e0 + CHUNK;
    for (int e = e0 + threadIdx.x; e < e1; e += 1024) {
        unsigned d = (unsigned)(dst[e] - r0);
        if (d < RANGE) {
            int s = src[e];
            int p = atomicAdd(&pos[d], 1);
            csr_src[p] = s;
        }
    }
}

// ---------------- GEMM: G0 = h@W0 + b, G1 = h@W1 (64 -> 64), 16 rows/block ----------------
__global__ __launch_bounds__(256) void k_gemm64(const float* __restrict__ h,
                                                const float* __restrict__ W0,
                                                const float* __restrict__ W1,
                                                const float* __restrict__ b,
                                                float* __restrict__ G0,
                                                float* __restrict__ G1) {
    __shared__ float sw0[64 * 64], sw1[64 * 64];
    __shared__ float sh[16 * 64];
    int t = threadIdx.x;
    for (int k = t; k < 64 * 64; k += 256) { sw0[k] = W0[k]; sw1[k] = W1[k]; }
    int i0 = blockIdx.x * 16;    // grid exactly N/16
    for (int k = t; k < 16 * 64; k += 256) sh[k] = h[i0 * 64 + k];
    __syncthreads();
    int r = t >> 6, c = t & 63;
    float a0[4], a1[4];
    float bc = b[c];
    #pragma unroll
    for (int p = 0; p < 4; p++) { a0[p] = bc; a1[p] = 0.f; }
    #pragma unroll
    for (int k = 0; k < 64; k++) {
        float w0 = sw0[k * 64 + c], w1 = sw1[k * 64 + c];
        #pragma unroll
        for (int p = 0; p < 4; p++) {
            float hv = sh[(r + 4 * p) * 64 + k];
            a0[p] += hv * w0;
            a1[p] += hv * w1;
        }
    }
    #pragma unroll
    for (int p = 0; p < 4; p++) {
        G0[(i0 + r + 4 * p) * 64 + c] = a0[p];
        G1[(i0 + r + 4 * p) * 64 + c] = a1[p];
    }
}

// ---------------- GEMM: 64 -> 40, 16 rows/block ----------------
__global__ __launch_bounds__(256) void k_gemm40(const float* __restrict__ h,
                                                const float* __restrict__ W0,
                                                const float* __restrict__ W1,
                                                const float* __restrict__ b,
                                                float* __restrict__ G0,
                                                float* __restrict__ G1) {
    __shared__ float sw0[64 * OUTC], sw1[64 * OUTC];
    __shared__ float sh[16 * 64];
    int t = threadIdx.x;
    for (int k = t; k < 64 * OUTC; k += 256) { sw0[k] = W0[k]; sw1[k] = W1[k]; }
    int i0 = blockIdx.x * 16;
    for (int k = t; k < 16 * 64; k += 256) sh[k] = h[i0 * 64 + k];
    __syncthreads();
    int r = t >> 6, c = t & 63;
    if (c >= OUTC) return;
    float a0[4], a1[4];
    float bc = b[c];
    #pragma unroll
    for (int p = 0; p < 4; p++) { a0[p] = bc; a1[p] = 0.f; }
    #pragma unroll
    for (int k = 0; k < 64; k++) {
        float w0 = sw0[k * OUTC + c], w1 = sw1[k * OUTC + c];
        #pragma unroll
        for (int p = 0; p < 4; p++) {
            float hv = sh[(r + 4 * p) * 64 + k];
            a0[p] += hv * w0;
            a1[p] += hv * w1;
        }
    }
    #pragma unroll
    for (int p = 0; p < 4; p++) {
        G0[(i0 + r + 4 * p) * OUTC + c] = a0[p];
        G1[(i0 + r + 4 * p) * OUTC + c] = a1[p];
    }
}

// ---------------- fused SpMM + epilogue (relu), 64 ch ----------------
// out[i] = relu( G0[i] + norm_loop[i]*G1[i] - scale * sum_{e: dst=i} G1[src_e] )
__global__ __launch_bounds__(256) void k_spmm64(const float* __restrict__ G0,
                                                const float* __restrict__ G1,
                                                const int* __restrict__ rowptr,
                                                const int* __restrict__ csr_src,
                                                const int* __restrict__ deg_src,
                                                const int* __restrict__ maxdeg,
                                                float* __restrict__ out) {
    int wave = threadIdx.x >> 6;
    int lane = threadIdx.x & 63;
    int i = blockIdx.x * 4 + wave;
    float scale = 1.0f / (float)(*maxdeg);
    float g0 = G0[i * 64 + lane];
    float g1 = G1[i * 64 + lane];
    int e0 = rowptr[i], e1 = rowptr[i + 1];
    float acc0 = 0.f, acc1 = 0.f;
    for (int base = e0; base < e1; base += 64) {
        int n = min(64, e1 - base);
        int idx = (base + lane < e1) ? csr_src[base + lane] : 0;
        int j = 0;
        for (; j + 4 <= n; j += 4) {
            int s0 = __shfl(idx, j);
            int s1 = __shfl(idx, j + 1);
            int s2 = __shfl(idx, j + 2);
            int s3 = __shfl(idx, j + 3);
            float a0 = G1[s0 * 64 + lane];
            float a1 = G1[s1 * 64 + lane];
            float a2 = G1[s2 * 64 + lane];
            float a3 = G1[s3 * 64 + lane];
            acc0 += a0 + a2;
            acc1 += a1 + a3;
        }
        for (; j < n; j++) {
            int s = __shfl(idx, j);
            acc0 += G1[s * 64 + lane];
        }
    }
    float nl = (float)deg_src[i] * scale - 1.0f;
    float v = g0 + nl * g1 - scale * (acc0 + acc1);
    out[i * 64 + lane] = fmaxf(v, 0.f);
}

// ---------------- fused SpMM + log_softmax, 40 ch ----------------
__global__ __launch_bounds__(256) void k_spmm40(const float* __restrict__ G0,
                                                const float* __restrict__ G1,
                                                const int* __restrict__ rowptr,
                                                const int* __restrict__ csr_src,
                                                const int* __restrict__ deg_src,
                                                const int* __restrict__ maxdeg,
                                                float* __restrict__ out) {
    int wave = threadIdx.x >> 6;
    int lane = threadIdx.x & 63;
    int i = blockIdx.x * 4 + wave;
    float scale = 1.0f / (float)(*maxdeg);
    bool act = lane < OUTC;
    float g0 = act ? G0[i * OUTC + lane] : 0.f;
    float g1 = act ? G1[i * OUTC + lane] : 0.f;
    int e0 = rowptr[i], e1 = rowptr[i + 1];
    float acc0 = 0.f, acc1 = 0.f;
    for (int base = e0; base < e1; base += 64) {
        int n = min(64, e1 - base);
        int idx = (base + lane < e1) ? csr_src[base + lane] : 0;
        int j = 0;
        for (; j + 4 <= n; j += 4) {
            int s0 = __shfl(idx, j);
            int s1 = __shfl(idx, j + 1);
            int s2 = __shfl(idx, j + 2);
            int s3 = __shfl(idx, j + 3);
            if (act) {
                float a0 = G1[s0 * OUTC + lane];
                float a1 = G1[s1 * OUTC + lane];
                float a2 = G1[s2 * OUTC + lane];
                float a3 = G1[s3 * OUTC + lane];
                acc0 += a0 + a2;
                acc1 += a1 + a3;
            }
        }
        for (; j < n; j++) {
            int s = __shfl(idx, j);
            if (act) acc0 += G1[s * OUTC + lane];
        }
    }
    float nl = (float)deg_src[i] * scale - 1.0f;
    float v = g0 + nl * g1 - scale * (acc0 + acc1);
    float x = act ? v : -INFINITY;
    float m = x;
    for (int off = 32; off; off >>= 1) m = fmaxf(m, __shfl_xor(m, off));
    float ex = act ? __expf(v - m) : 0.f;
    float s = ex;
    for (int off = 32; off; off >>= 1) s += __shfl_xor(s, off);
    if (act) out[i * OUTC + lane] = v - m - __logf(s);
}

// ---------------- launch ----------------

extern "C" void kernel_launch(void* const* d_in, const int* in_sizes, int n_in,
                              void* d_out, int out_size, void* d_ws, size_t ws_size,
                              hipStream_t stream) {
    const float* x   = (const float*)d_in[0];
    const int* ei    = (const int*)d_in[1];
    const int* src   = ei;
    const int* dst   = ei + N_EDGES;
    const float* W0_0 = (const float*)d_in[2];
    const float* W1_0 = (const float*)d_in[3];
    const float* b_0  = (const float*)d_in[4];
    const float* W0_1 = (const float*)d_in[5];
    const float* W1_1 = (const float*)d_in[6];
    const float* b_1  = (const float*)d_in[7];
    const float* W0_2 = (const float*)d_in[8];
    const float* W1_2 = (const float*)d_in[9];
    const float* b_2  = (const float*)d_in[10];
    float* outp = (float*)d_out;

    // workspace layout
    int* ip = (int*)d_ws;
    int* deg_src  = ip;                      // N
    int* rowptr   = ip + 100000;             // N+1 (padded to 100032)
    int* blocksum = ip + 200064;             // 128
    int* maxdeg   = ip + 200192;             // 1 (padded to 64)
    int* csr_src  = ip + 200256;             // E
    float* fb = (float*)(ip + 1800256);
    float* hbuf = fb;                        // N*64
    float* G0   = fb + 6400000;              // N*64
    float* G1   = fb + 12800000;             // N*64
    // during CSR build, reuse G0/G1 space for histograms (NC*NPAD = 3.67M ints each)
    int* Hs = (int*)G0;
    int* Hd = (int*)G1;

    hipMemsetAsync(maxdeg, 0, sizeof(int), stream);

    k_hist<<<dim3(NC, NR, 2), 1024, 0, stream>>>(src, dst, Hs, Hd);
    k_degsrc<<<(N_NODES + 255) / 256, 256, 0, stream>>>(Hs, deg_src, maxdeg);
    k_scan1<<<SCAN_NBLK, SCAN_BLOCK, 0, stream>>>(Hd, rowptr, blocksum);
    k_scan2<<<1, SCAN_BLOCK, 0, stream>>>(rowptr, blocksum);
    k_basepos<<<(N_NODES + 255) / 256, 256, 0, stream>>>(rowptr, Hd);
    k_fill2<<<dim3(NC, NR), 1024, 0, stream>>>(src, dst, Hd, csr_src);

    const int GN = N_NODES / 4;    // 25000, exact
    const int GG = N_NODES / 16;   // 6250, exact

    // layer 0: x -> hbuf
    k_gemm64<<<GG, 256, 0, stream>>>(x, W0_0, W1_0, b_0, G0, G1);
    k_spmm64<<<GN, 256, 0, stream>>>(G0, G1, rowptr, csr_src, deg_src, maxdeg, hbuf);
    // layer 1: hbuf -> hbuf (in-place safe: spmm reads only G0/G1)
    k_gemm64<<<GG, 256, 0, stream>>>(hbuf, W0_1, W1_1, b_1, G0, G1);
    k_spmm64<<<GN, 256, 0, stream>>>(G0, G1, rowptr, csr_src, deg_src, maxdeg, hbuf);
    // layer 2: hbuf -> out (40 ch + log_softmax)
    k_gemm40<<<GG, 256, 0, stream>>>(hbuf, W0_2, W1_2, b_2, G0, G1);
    k_spmm40<<<GN, 256, 0, stream>>>(G0, G1, rowptr, csr_src, deg_src, maxdeg, outp);
}